// Round 14
// baseline (33.409 us; speedup 1.0000x reference)
//
#include <hip/hip_runtime.h>
#include <hip/hip_bf16.h>
#include <stdint.h>

// Problem constants (fixed by reference)
#define BB 4
#define LL 256
#define WW 256
#define HH 768
#define NL 10
#define LT 16           // L-rows per score block
#define WT 64           // W-cols per score block
#define ASTRIDE 776     // A_lds row stride in ushorts (1552B, conflict-benign)

typedef __attribute__((ext_vector_type(8))) short bf16x8;   // 8 bf16 (4 VGPRs)
typedef __attribute__((ext_vector_type(4))) float f32x4;    // MFMA C/D

__device__ inline unsigned short f2bf(float x) {            // RNE via HW cvt
    return __builtin_bit_cast(unsigned short, __float2bfloat16(x));
}
__device__ inline float bf2f(unsigned short u) {
    return __builtin_bit_cast(float, (uint32_t)u << 16);
}
__device__ inline bf16x8 pack8(float4 a, float4 b) {
    union { bf16x8 v; unsigned short u[8]; } r;
    r.u[0] = f2bf(a.x); r.u[1] = f2bf(a.y); r.u[2] = f2bf(a.z); r.u[3] = f2bf(a.w);
    r.u[4] = f2bf(b.x); r.u[5] = f2bf(b.y); r.u[6] = f2bf(b.z); r.u[7] = f2bf(b.w);
    return r.v;
}

// ---------------------------------------------------------------------------
// ONE kernel. Block = (b, 16 L-rows, 64 W-cols) as in R9 (A in LDS, B direct,
// XCD swizzle). The 4 wt-siblings of each (b,lt) publish bucket partials to
// agent-scope slots; the LAST sibling (atomic ticket) sums them in fixed wt
// order (deterministic), normalizes, and runs the 10-row epilogue + residual
// (residual from its own A_lds bf16 staging). No combine kernel, no roundtrip
// through a second dispatch. No spin-waits: no deadlock possible.
// ---------------------------------------------------------------------------
__global__ __launch_bounds__(256, 1) void score_fused_kernel(
    const int* __restrict__ word_seq,           // [B,W]
    const float* __restrict__ hidden,           // [B,L,H]
    const float* __restrict__ emb_a,            // [50000,H]
    const int* __restrict__ label,              // [B,L,W]
    const float* __restrict__ mask,             // [B,L,W]
    const float* __restrict__ emb_c,            // [10,H]
    float* __restrict__ out,                    // [B,L,H]
    float* __restrict__ s_out,                  // ws: [64][4][160]
    int* __restrict__ cnt)                      // ws: [64] tickets (pre-zeroed)
{
    __shared__ unsigned short A_lds[LT * ASTRIDE];   // 24832 B
    __shared__ float s_lds[LT][NL];
    __shared__ float inv[LT];
    __shared__ int ticket;

    const int t    = threadIdx.x;
    const int wave = t >> 6, lane = t & 63;
    const int g    = lane >> 4, c = lane & 15;

    // ---- XCD-grouped swizzle decode (bijective on [0,256)) ----
    const int x    = blockIdx.x;
    const int G    = (x & 7) + 8 * (x >> 7);
    const int lt   = (x >> 3) & 15;
    const int b    = G >> 2, wt = G & 3;
    const int l0   = lt * LT;

    if (t < LT * NL) ((float*)s_lds)[t] = 0.f;

    // ---- stage A: 16 rows x 768 fp32 -> bf16 LDS, 1536 8-elem units ----
    #pragma unroll
    for (int i = 0; i < 6; ++i) {
        int idx = t + i * 256;
        int r = idx / 96, u = idx - r * 96;
        const float4* src = reinterpret_cast<const float4*>(
            hidden + ((size_t)(b * LL) + l0 + r) * HH + u * 8);
        float4 v0 = src[0], v1 = src[1];
        *reinterpret_cast<bf16x8*>(&A_lds[r * ASTRIDE + u * 8]) = pack8(v0, v1);
    }

    // ---- B pointer: one gathered emb_a row per (wave,c) ----
    const int wcol = wt * WT + wave * 16 + c;
    const int wrow = word_seq[b * WW + wcol];
    const float4* bp = reinterpret_cast<const float4*>(
        emb_a + (size_t)wrow * HH + g * 8);      // +8 f4 per k-step

    // ---- early-issue epilogue mask/label loads (hide cold-HBM latency) ----
    float mval[4]; int lval[4];
    #pragma unroll
    for (int r = 0; r < 4; ++r) {
        size_t idx = ((size_t)(b * LL) + l0 + g * 4 + r) * WW + wcol;
        mval[r] = mask[idx];
        lval[r] = label[idx];
    }

    // ---- depth-4 rotating prefetch for B ----
    float4 rb0[4], rb1[4];
    #pragma unroll
    for (int i = 0; i < 4; ++i) { rb0[i] = bp[i * 8]; rb1[i] = bp[i * 8 + 1]; }

    __syncthreads();    // A_lds staged, s_lds zeroed

    f32x4 acc = {0.f, 0.f, 0.f, 0.f};
    #pragma unroll
    for (int k = 0; k < 24; ++k) {
        const int s = k & 3;
        bf16x8 bv = pack8(rb0[s], rb1[s]);
        bf16x8 av = *reinterpret_cast<const bf16x8*>(
            &A_lds[c * ASTRIDE + (4 * k + g) * 8]);
        if (k + 4 < 24) { rb0[s] = bp[(k + 4) * 8]; rb1[s] = bp[(k + 4) * 8 + 1]; }
        acc = __builtin_amdgcn_mfma_f32_16x16x32_bf16(av, bv, acc, 0, 0, 0);
    }

    // ---- masked exp + label buckets (C/D: col = lane&15, row = g*4+reg) ----
    const float scale = 0.03608439182435161f;  // 1/sqrt(768)
    #pragma unroll
    for (int r = 0; r < 4; ++r) {
        int lrow = g * 4 + r;
        float m = fminf(fmaxf(mval[r], 0.f), 1.f);
        float e = __expf(acc[r] * scale) * m;
        atomicAdd(&s_lds[lrow][lval[r]], e);
    }
    __syncthreads();

    // ---- publish partial to agent-visible slot (b,lt,wt) ----
    const int grp  = b * 16 + lt;
    if (t < LT * NL)
        __hip_atomic_store(&s_out[((size_t)grp * 4 + wt) * (LT * NL) + t],
                           ((float*)s_lds)[t],
                           __ATOMIC_RELAXED, __HIP_MEMORY_SCOPE_AGENT);
    __syncthreads();    // all slot stores issued before the ticket

    if (t == 0) {
        __threadfence();    // agent release for the block's stores
        ticket = __hip_atomic_fetch_add(&cnt[grp], 1,
                                        __ATOMIC_ACQ_REL, __HIP_MEMORY_SCOPE_AGENT);
    }
    __syncthreads();
    if (ticket != 3) return;    // only the LAST sibling proceeds (uniform)

    // ---- winner: sum 4 partials in FIXED wt order (deterministic) ----
    __threadfence();            // acquire side
    if (t < LT * NL) {
        const size_t base = (size_t)grp * 4 * (LT * NL);
        float v = 0.f;
        #pragma unroll
        for (int w2 = 0; w2 < 4; ++w2)
            v += __hip_atomic_load(&s_out[base + w2 * (LT * NL) + t],
                                   __ATOMIC_RELAXED, __HIP_MEMORY_SCOPE_AGENT);
        ((float*)s_lds)[t] = v;
    }
    __syncthreads();
    if (t < LT) {
        float d = 1e-10f;
        #pragma unroll
        for (int k = 0; k < NL; ++k) d += s_lds[t][k];
        inv[t] = 1.f / d;
    }
    __syncthreads();
    if (t < LT * NL) ((float*)s_lds)[t] *= inv[t / NL];
    __syncthreads();

    // ---- epilogue: 16 rows x 192 float4 cols; residual from A_lds bf16 ----
    if (t < 192) {
        const float4* ec4 = reinterpret_cast<const float4*>(emb_c);
        float4* o4 = reinterpret_cast<float4*>(out);
        float4 ec[NL];
        #pragma unroll
        for (int k = 0; k < NL; ++k) ec[k] = ec4[k * 192 + t];
        #pragma unroll
        for (int r = 0; r < LT; ++r) {
            ushort4 hb4 = *reinterpret_cast<const ushort4*>(&A_lds[r * ASTRIDE + t * 4]);
            float4 o = { bf2f(hb4.x), bf2f(hb4.y), bf2f(hb4.z), bf2f(hb4.w) };
            #pragma unroll
            for (int k = 0; k < NL; ++k) {
                float w = s_lds[r][k];
                o.x = fmaf(w, ec[k].x, o.x); o.y = fmaf(w, ec[k].y, o.y);
                o.z = fmaf(w, ec[k].z, o.z); o.w = fmaf(w, ec[k].w, o.w);
            }
            o4[((size_t)(b * LL) + l0 + r) * 192 + t] = o;
        }
    }
}

extern "C" void kernel_launch(void* const* d_in, const int* in_sizes, int n_in,
                              void* d_out, int out_size, void* d_ws, size_t ws_size,
                              hipStream_t stream) {
    const int*   word_seq = (const int*)d_in[0];
    const float* hidden   = (const float*)d_in[1];
    const int*   label    = (const int*)d_in[2];
    const float* mask     = (const float*)d_in[3];
    const float* emb_a    = (const float*)d_in[4];
    const float* emb_c    = (const float*)d_in[5];
    float*       out      = (float*)d_out;

    // ws layout: [0,256): int cnt[64]; [256, ...): float s_out[64][4][160]
    int*   cnt   = (int*)d_ws;
    float* s_out = (float*)((char*)d_ws + 256);

    hipMemsetAsync(cnt, 0, 64 * sizeof(int), stream);   // tickets start at 0
    score_fused_kernel<<<BB * 16 * 4, 256, 0, stream>>>(
        word_seq, hidden, emb_a, label, mask, emb_c, out, s_out, cnt);
}

// Round 15
// 16.900 us; speedup vs baseline: 1.9768x; 1.9768x over previous
//
#include <hip/hip_runtime.h>
#include <hip/hip_bf16.h>
#include <stdint.h>

// Problem constants (fixed by reference)
#define BB 4
#define LL 256
#define WW 256
#define HH 768
#define NL 10
#define LT 16           // L-rows per score block
#define WT 64           // W-cols per score block
#define ASTRIDE 776     // A_lds row stride in ushorts (1552B, conflict-benign)

typedef __attribute__((ext_vector_type(8))) short bf16x8;   // 8 bf16 (4 VGPRs)
typedef __attribute__((ext_vector_type(4))) float f32x4;    // MFMA C/D

__device__ inline unsigned short f2bf(float x) {            // RNE via HW cvt
    return __builtin_bit_cast(unsigned short, __float2bfloat16(x));
}
__device__ inline bf16x8 pack8(float4 a, float4 b) {
    union { bf16x8 v; unsigned short u[8]; } r;
    r.u[0] = f2bf(a.x); r.u[1] = f2bf(a.y); r.u[2] = f2bf(a.z); r.u[3] = f2bf(a.w);
    r.u[4] = f2bf(b.x); r.u[5] = f2bf(b.y); r.u[6] = f2bf(b.z); r.u[7] = f2bf(b.w);
    return r.v;
}

// ---------------------------------------------------------------------------
// K1: score (R9 structure — measured best). Block = (b, 16 L-rows, 64 W-cols);
// 4 waves, one 16x16 C-tile each.
//  - A (hidden rows) staged once per block in LDS as bf16 (padded stride).
//  - B (gathered emb_a rows) loaded direct fp32, depth-4 rotating prefetch.
//  - XCD swizzle: 16 lt-blocks sharing (b,wt) -> same XCD (L2-resident B).
// Writes UNNORMALIZED buckets s[16][10]; denominator D = sum_k s_k later.
// ---------------------------------------------------------------------------
__global__ __launch_bounds__(256, 1) void score_kernel(
    const int* __restrict__ word_seq,           // [B,W]
    const float* __restrict__ hidden,           // [B,L,H]
    const float* __restrict__ emb_a,            // [50000,H]
    const int* __restrict__ label,              // [B,L,W]
    const float* __restrict__ mask,             // [B,L,W]
    float* __restrict__ s_out)                  // [256 logical][16][10]
{
    __shared__ unsigned short A_lds[LT * ASTRIDE];   // 24832 B
    __shared__ float s_lds[LT][NL];

    const int t    = threadIdx.x;
    const int wave = t >> 6, lane = t & 63;
    const int g    = lane >> 4, c = lane & 15;

    // ---- XCD-grouped swizzle decode (bijective on [0,256)) ----
    const int x    = blockIdx.x;
    const int G    = (x & 7) + 8 * (x >> 7);
    const int lt   = (x >> 3) & 15;
    const int b    = G >> 2, wt = G & 3;
    const int l0   = lt * LT;

    if (t < LT * NL) ((float*)s_lds)[t] = 0.f;

    // ---- stage A: 16 rows x 768 fp32 -> bf16 LDS, 1536 8-elem units ----
    #pragma unroll
    for (int i = 0; i < 6; ++i) {
        int idx = t + i * 256;
        int r = idx / 96, u = idx - r * 96;
        const float4* src = reinterpret_cast<const float4*>(
            hidden + ((size_t)(b * LL) + l0 + r) * HH + u * 8);
        float4 v0 = src[0], v1 = src[1];
        *reinterpret_cast<bf16x8*>(&A_lds[r * ASTRIDE + u * 8]) = pack8(v0, v1);
    }

    // ---- B pointer: one gathered emb_a row per (wave,c) ----
    const int wcol = wt * WT + wave * 16 + c;
    const int wrow = word_seq[b * WW + wcol];
    const float4* bp = reinterpret_cast<const float4*>(
        emb_a + (size_t)wrow * HH + g * 8);      // +8 f4 per k-step

    // ---- depth-4 rotating prefetch for B (statically indexed) ----
    float4 rb0[4], rb1[4];
    #pragma unroll
    for (int i = 0; i < 4; ++i) { rb0[i] = bp[i * 8]; rb1[i] = bp[i * 8 + 1]; }

    __syncthreads();    // A_lds staged, s_lds zeroed

    f32x4 acc = {0.f, 0.f, 0.f, 0.f};
    #pragma unroll
    for (int k = 0; k < 24; ++k) {
        const int s = k & 3;
        bf16x8 bv = pack8(rb0[s], rb1[s]);
        bf16x8 av = *reinterpret_cast<const bf16x8*>(
            &A_lds[c * ASTRIDE + (4 * k + g) * 8]);
        if (k + 4 < 24) { rb0[s] = bp[(k + 4) * 8]; rb1[s] = bp[(k + 4) * 8 + 1]; }
        acc = __builtin_amdgcn_mfma_f32_16x16x32_bf16(av, bv, acc, 0, 0, 0);
    }

    // C/D layout (m89): col = lane&15 (w), row = (lane>>4)*4 + reg (l)
    const float scale = 0.03608439182435161f;  // 1/sqrt(768)
    #pragma unroll
    for (int r = 0; r < 4; ++r) {
        int lrow = g * 4 + r;
        size_t idx = ((size_t)(b * LL) + l0 + lrow) * WW + wcol;
        float m = mask[idx];
        m = fminf(fmaxf(m, 0.f), 1.f);
        float e = __expf(acc[r] * scale) * m;
        atomicAdd(&s_lds[lrow][label[idx]], e);
    }
    __syncthreads();

    // logical slot (b,lt,wt) so combine's indexing is unchanged
    if (t < LT * NL) {
        size_t sidx = ((size_t)((b * 16 + lt) * 4 + wt)) * (LT * NL) + t;
        s_out[sidx] = ((float*)s_lds)[t];
    }
}

// ---------------------------------------------------------------------------
// K2: combine W-tile partials, normalize, 10-row epilogue + residual.
// Block = (b, 16 L-rows, 192 h-cols); grid 256, 192 threads (3 waves).
// ---------------------------------------------------------------------------
__global__ __launch_bounds__(192, 4) void combine_kernel(
    const float* __restrict__ s_in,     // [256][16][10]
    const float* __restrict__ hidden,   // [B,L,H]
    const float* __restrict__ emb_c,    // [10,H]
    float* __restrict__ out)            // [B,L,H]
{
    __shared__ float sp[LT][NL];
    __shared__ float inv[LT];
    const int t = threadIdx.x;
    const int bid = blockIdx.x;
    const int hq = bid & 3, lt = (bid >> 2) & 15, b = bid >> 6;
    const int l0 = lt * LT;
    const int h = hq * 192 + t;

    if (t < LT * NL) {
        size_t base = ((size_t)(b * 16 + lt)) * 4 * (LT * NL);  // wt=0 slot
        float v = 0.f;
        #pragma unroll
        for (int wt = 0; wt < 4; ++wt) v += s_in[base + wt * (LT * NL) + t];
        ((float*)sp)[t] = v;
    }
    __syncthreads();
    if (t < LT) {
        float d = 1e-10f;
        #pragma unroll
        for (int k = 0; k < NL; ++k) d += sp[t][k];
        inv[t] = 1.f / d;
    }
    __syncthreads();

    float ec[NL];
    #pragma unroll
    for (int k = 0; k < NL; ++k) ec[k] = emb_c[k * HH + h];
    #pragma unroll
    for (int r = 0; r < LT; ++r) {
        size_t base = ((size_t)(b * LL) + l0 + r) * HH + h;
        float acc = 0.f;
        #pragma unroll
        for (int k = 0; k < NL; ++k) acc = fmaf(sp[r][k], ec[k], acc);
        out[base] = hidden[base] + acc * inv[r];
    }
}

extern "C" void kernel_launch(void* const* d_in, const int* in_sizes, int n_in,
                              void* d_out, int out_size, void* d_ws, size_t ws_size,
                              hipStream_t stream) {
    const int*   word_seq = (const int*)d_in[0];
    const float* hidden   = (const float*)d_in[1];
    const int*   label    = (const int*)d_in[2];
    const float* mask     = (const float*)d_in[3];
    const float* emb_a    = (const float*)d_in[4];
    const float* emb_c    = (const float*)d_in[5];
    float*       out      = (float*)d_out;

    float* s_out = (float*)d_ws;   // 256*160 fp32 = 160 KB scratch

    score_kernel<<<BB * 16 * 4, 256, 0, stream>>>(
        word_seq, hidden, emb_a, label, mask, s_out);
    combine_kernel<<<BB * 16 * 4, 192, 0, stream>>>(s_out, hidden, emb_c, out);
}